// Round 9
// baseline (599.761 us; speedup 1.0000x reference)
//
#include <hip/hip_runtime.h>

// Problem constants (from reference)
#define BATCH 2
#define HH 512
#define WW 512
#define NIN 64
#define NOUT 64
#define N_NZ 131072
#define N_MASK 131072
#define NPIX (BATCH * HH * WW)   // 524288

// Spatial tiling
#define TS 16                    // tile side (pixels)
#define TPX (TS * TS)            // 256 px per tile
#define NTY (HH / TS)            // 32
#define NTX (WW / TS)            // 32
#define NTILES (BATCH * NTY * NTX)  // 2048
#define CAP 256                  // entry capacity per tile (mean ~81, max ~130)
#define CNT_STRIDE 16            // one counter per 64B line -> no line contention

// d_ws layout (~6.2 MB total; R8 proved >=36 MB available):
//   [0, 2MB)        float mask[NPIX]
//   [+128KB)        int   tcnt[NTILES*CNT_STRIDE]
//   [+4MB)          uint2 tentry[NTILES*CAP]
//   [+72KB)         bf16  kt[9][NOUT][NIN]
#define WS_MASK_OFF  0
#define WS_TCNT_OFF  ((size_t)NPIX * 4)                          // 2097152
#define WS_TENT_OFF  (WS_TCNT_OFF + (size_t)NTILES * CNT_STRIDE * 4)
#define WS_KT_OFF    (WS_TENT_OFF + (size_t)NTILES * CAP * 8)
#define WS_END       (WS_KT_OFF + (size_t)9 * NIN * NOUT * 2)
#define WS_ZERO_SPAN WS_TENT_OFF   // mask + tcnt need zeroing

typedef short s8v  __attribute__((ext_vector_type(8)));   // 8 bf16
typedef float f4v  __attribute__((ext_vector_type(4)));   // 4 fp32 acc

__device__ __forceinline__ short f2bf(float f) {
    unsigned u = __builtin_bit_cast(unsigned, f);
    unsigned r = u + 0x7FFFu + ((u >> 16) & 1u);   // RNE
    return (short)(r >> 16);
}

// ---------------------------------------------------------------------------
// Mask scatter:  mask[b,y,x] += mask_values[n]
// ---------------------------------------------------------------------------
__global__ void mask_scatter_kernel(const float* __restrict__ mv,
                                    const int* __restrict__ midx,
                                    float* __restrict__ mask) {
    int n = blockIdx.x * blockDim.x + threadIdx.x;
    if (n < N_MASK) {
        int b = midx[n * 3 + 0];
        int y = midx[n * 3 + 1];
        int x = midx[n * 3 + 2];
        atomicAdd(&mask[(b * HH + y) * WW + x], mv[n]);
    }
}

// ---------------------------------------------------------------------------
// Weight transpose + bf16 convert:  kt[tap][c][i] = bf16(kern[tap][i][c])
// ---------------------------------------------------------------------------
__global__ void convert_kt_kernel(const float* __restrict__ kern,
                                  short* __restrict__ kt) {
    int t = blockIdx.x * 256 + threadIdx.x;
    if (t < 9 * NIN * NOUT) {
        int tap = t >> 12;
        int rem = t & 4095;
        int c = rem >> 6;          // out channel
        int i = rem & 63;          // in channel
        kt[tap * 4096 + c * 64 + i] = f2bf(kern[tap * 4096 + i * 64 + c]);
    }
}

// ---------------------------------------------------------------------------
// Bin points into the tiles their clipped 3x3 footprint touches (1..4 tiles,
// avg ~1.27). Counters are padded to one per 64B line: the 166K atomicAdds
// spread over 2048 independent lines (~81 ops/line) - no serialization wall.
// ---------------------------------------------------------------------------
__global__ void fill_bins_kernel(const int* __restrict__ idx,
                                 int* __restrict__ tcnt,
                                 uint2* __restrict__ tentry) {
    int p = blockIdx.x * 256 + threadIdx.x;
    if (p >= N_NZ) return;
    int b = idx[p * 3 + 0];
    int y = idx[p * 3 + 1];
    int x = idx[p * 3 + 2];
    int ty0 = max(y - 1, 0) >> 4;
    int ty1 = min(y + 1, HH - 1) >> 4;
    int tx0 = max(x - 1, 0) >> 4;
    int tx1 = min(x + 1, WW - 1) >> 4;
    uint2 e;
    e.x = (unsigned)p;                                   // point id
    e.y = ((unsigned)b << 18) | ((unsigned)y << 9) | (unsigned)x;
    for (int ty = ty0; ty <= ty1; ++ty)
        for (int tx = tx0; tx <= tx1; ++tx) {
            int t = (b * NTY + ty) * NTX + tx;
            int pos = atomicAdd(&tcnt[t * CNT_STRIDE], 1);
            if (pos < CAP) tentry[t * CAP + pos] = e;
        }
}

// ---------------------------------------------------------------------------
// Tiled conv + fused epilogue. One block (4 waves) per 16x16 output tile.
// LDS holds the full 256px x 64ch fp32 accumulator (64 KB, 2 blocks/CU).
// Per 64-entry chunk: R8's proven MFMA datapath (A = 16 value rows bf16,
// B = tap weights transposed) -> rows landing in-tile are ds_add_f32'ed.
// Every (point,tap) lands in exactly ONE tile (its clipped dest pixel's),
// so global atomics are eliminated entirely. Epilogue (acc+m*bias)*m is
// fused into the tile writeout: one coalesced 4KB store per tile row.
// Layouts (R8-verified, absmax 0.031): A[m=lane&15][k=q*8+j],
// B[k=q*8+j][n=lane&15], C/D col=lane&15 row=q*4+reg.
// ---------------------------------------------------------------------------
__global__ __launch_bounds__(256, 2) void conv_tile_kernel(
        const float* __restrict__ values,   // (N_NZ, NIN) fp32
        const short* __restrict__ kt,       // (9, NOUT, NIN) bf16 transposed
        const float* __restrict__ mask,     // (NPIX,)
        const float* __restrict__ bias,     // (NOUT,)
        const int* __restrict__ tcnt,
        const uint2* __restrict__ tentry,
        float* __restrict__ out) {          // (B,H,W,NOUT)
    __shared__ float acc[TPX * NOUT];       // 64 KB
    __shared__ float lmask[TPX];            // 1 KB

    const int tid = threadIdx.x;
    const int t  = blockIdx.x;
    const int b  = t >> 10;
    const int ty = (t >> 5) & 31;
    const int tx = t & 31;
    const int oy = ty * TS, ox = tx * TS;

    // zero accumulator (4096 float4 / 256 threads = 16 each)
    float4* accv = (float4*)acc;
#pragma unroll
    for (int i = 0; i < 16; ++i)
        accv[i * 256 + tid] = make_float4(0.f, 0.f, 0.f, 0.f);
    // preload this tile's mask values
    {
        int ly = tid >> 4, lx = tid & 15;
        lmask[tid] = mask[(size_t)(b * HH + oy + ly) * WW + ox + lx];
    }
    __syncthreads();

    const int wid = tid >> 6, lane = tid & 63, q = lane >> 4, col = lane & 15;
    const int cnt = min(tcnt[t * CNT_STRIDE], CAP);

    for (int base = 0; base < cnt; base += 64) {
        const int e = base + wid * 16 + col;   // this lane's entry
        const bool alive = (e < cnt);
        const uint2 ent = tentry[t * CAP + (alive ? e : 0)];
        const int pid = (int)ent.x;
        const int ey  = (int)((ent.y >> 9) & 511);
        const int ex  = (int)(ent.y & 511);

        // A fragments: 16 points x 64 in-ch, fp32 -> bf16
        const float* vrow = values + (size_t)pid * NIN + q * 8;
        s8v a0, a1;
#pragma unroll
        for (int j = 0; j < 8; ++j) {
            a0[j] = f2bf(vrow[j]);
            a1[j] = f2bf(vrow[32 + j]);
        }

        for (int tap = 0; tap < 9; ++tap) {
            const int ky = tap / 3, kx = tap % 3;
            const int sy = min(max(ey + ky - 1, 0), HH - 1);
            const int sx = min(max(ex + kx - 1, 0), WW - 1);
            const int py = sy - oy, px = sx - ox;
            const int loff = (alive && py >= 0 && py < TS && px >= 0 && px < TS)
                                 ? (py * TS + px) : -1;
            if (__ballot(loff >= 0) == 0ULL) continue;

            const short* kb = kt + tap * 4096 + col * 64 + q * 8;
            f4v c0 = {0.f,0.f,0.f,0.f}, c1 = {0.f,0.f,0.f,0.f};
            f4v c2 = {0.f,0.f,0.f,0.f}, c3 = {0.f,0.f,0.f,0.f};

            s8v b0a = *(const s8v*)(kb + 0 * 1024);
            s8v b0b = *(const s8v*)(kb + 0 * 1024 + 32);
            c0 = __builtin_amdgcn_mfma_f32_16x16x32_bf16(a0, b0a, c0, 0, 0, 0);
            c0 = __builtin_amdgcn_mfma_f32_16x16x32_bf16(a1, b0b, c0, 0, 0, 0);
            s8v b1a = *(const s8v*)(kb + 1 * 1024);
            s8v b1b = *(const s8v*)(kb + 1 * 1024 + 32);
            c1 = __builtin_amdgcn_mfma_f32_16x16x32_bf16(a0, b1a, c1, 0, 0, 0);
            c1 = __builtin_amdgcn_mfma_f32_16x16x32_bf16(a1, b1b, c1, 0, 0, 0);
            s8v b2a = *(const s8v*)(kb + 2 * 1024);
            s8v b2b = *(const s8v*)(kb + 2 * 1024 + 32);
            c2 = __builtin_amdgcn_mfma_f32_16x16x32_bf16(a0, b2a, c2, 0, 0, 0);
            c2 = __builtin_amdgcn_mfma_f32_16x16x32_bf16(a1, b2b, c2, 0, 0, 0);
            s8v b3a = *(const s8v*)(kb + 3 * 1024);
            s8v b3b = *(const s8v*)(kb + 3 * 1024 + 32);
            c3 = __builtin_amdgcn_mfma_f32_16x16x32_bf16(a0, b3a, c3, 0, 0, 0);
            c3 = __builtin_amdgcn_mfma_f32_16x16x32_bf16(a1, b3b, c3, 0, 0, 0);

            // D row = q*4+r (point), channel = tile16*n + col -> LDS add
#pragma unroll
            for (int r = 0; r < 4; ++r) {
                const int mr = q * 4 + r;
                const int lp = __shfl(loff, mr);   // dest px of point row mr
                if (lp >= 0) {
                    float* a = acc + lp * NOUT + col;
                    atomicAdd(a + 0,  c0[r]);
                    atomicAdd(a + 16, c1[r]);
                    atomicAdd(a + 32, c2[r]);
                    atomicAdd(a + 48, c3[r]);
                }
            }
        }
    }
    __syncthreads();

    // Fused epilogue + writeout: iteration i writes tile row i (4KB, coalesced)
    const float4* bias4 = (const float4*)bias;
    const size_t rowbase = (size_t)(b * HH + oy) * WW + ox;   // pixel index
#pragma unroll
    for (int i = 0; i < 16; ++i) {
        const int f = i * 256 + tid;      // float4 index within tile
        const int c4 = f & 15;
        const int pxl = f >> 4;           // local pixel
        const int ly = pxl >> 4, lx = pxl & 15;
        const float m = lmask[pxl];
        float4 v = make_float4(0.f, 0.f, 0.f, 0.f);
        if (m != 0.f) {
            const float4 av = accv[f];
            const float4 bb = bias4[c4];
            v.x = (av.x + m * bb.x) * m;
            v.y = (av.y + m * bb.y) * m;
            v.z = (av.z + m * bb.z) * m;
            v.w = (av.w + m * bb.w) * m;
        }
        ((float4*)out)[(rowbase + (size_t)ly * WW + lx) * 16 + c4] = v;
    }
}

extern "C" void kernel_launch(void* const* d_in, const int* in_sizes, int n_in,
                              void* d_out, int out_size, void* d_ws, size_t ws_size,
                              hipStream_t stream) {
    const float* values      = (const float*)d_in[0];
    const float* kern        = (const float*)d_in[1];
    const float* bias        = (const float*)d_in[2];
    const float* mask_values = (const float*)d_in[3];
    const int*   indices     = (const int*)d_in[4];
    const int*   mask_idx    = (const int*)d_in[5];
    float* out = (float*)d_out;

    char* ws = (char*)d_ws;
    float* mask   = (float*)(ws + WS_MASK_OFF);
    int*   tcnt   = (int*)(ws + WS_TCNT_OFF);
    uint2* tentry = (uint2*)(ws + WS_TENT_OFF);
    short* kt     = (short*)(ws + WS_KT_OFF);

    // zero mask + tile counters (2.1 MB) — no 128 MB / 36 MB memsets anymore
    hipMemsetAsync(ws, 0, WS_ZERO_SPAN, stream);

    mask_scatter_kernel<<<(N_MASK + 255) / 256, 256, 0, stream>>>(
        mask_values, mask_idx, mask);
    fill_bins_kernel<<<(N_NZ + 255) / 256, 256, 0, stream>>>(
        indices, tcnt, tentry);
    convert_kt_kernel<<<(9 * NIN * NOUT + 255) / 256, 256, 0, stream>>>(
        kern, kt);

    conv_tile_kernel<<<NTILES, 256, 0, stream>>>(
        values, kt, mask, bias, tcnt, tentry, out);
}

// Round 10
// 276.083 us; speedup vs baseline: 2.1724x; 2.1724x over previous
//
#include <hip/hip_runtime.h>

// Problem constants (from reference)
#define BATCH 2
#define HH 512
#define WW 512
#define NIN 64
#define NOUT 64
#define N_NZ 131072
#define N_MASK 131072
#define NPIX (BATCH * HH * WW)   // 524288
#define MAX_ALIVE N_MASK

// d_ws layout:
//   [0,256)            int counter
//   [256, +2MB)        float mask[NPIX]
//   [.., +2MB)         int   slot[NPIX]
//   [.., +32MB)        float compact[MAX_ALIVE*NOUT]
//   [.., +72KB)        bf16  kt[9][NOUT][NIN]  (transposed weights)
#define WS_MASK_OFF   256
#define WS_SLOT_OFF   (WS_MASK_OFF + (size_t)NPIX * 4)
#define WS_CMP_OFF    (WS_SLOT_OFF + (size_t)NPIX * 4)
#define WS_KT_OFF     (WS_CMP_OFF + (size_t)MAX_ALIVE * NOUT * 4)
#define WS_NEED       (WS_KT_OFF + (size_t)9 * NIN * NOUT * 2)

typedef short s8v  __attribute__((ext_vector_type(8)));   // 8 bf16
typedef float f4v  __attribute__((ext_vector_type(4)));   // 4 fp32 acc

__device__ __forceinline__ short f2bf(float f) {
    unsigned u = __builtin_bit_cast(unsigned, f);
    unsigned r = u + 0x7FFFu + ((u >> 16) & 1u);   // RNE
    return (short)(r >> 16);
}

// ---------------------------------------------------------------------------
// Mask scatter:  mask[b,y,x] += mask_values[n]
// ---------------------------------------------------------------------------
__global__ void mask_scatter_kernel(const float* __restrict__ mv,
                                    const int* __restrict__ midx,
                                    float* __restrict__ mask) {
    int n = blockIdx.x * blockDim.x + threadIdx.x;
    if (n < N_MASK) {
        int b = midx[n * 3 + 0];
        int y = midx[n * 3 + 1];
        int x = midx[n * 3 + 2];
        atomicAdd(&mask[(b * HH + y) * WW + x], mv[n]);
    }
}

// ---------------------------------------------------------------------------
// Slot assignment: block-aggregated scan, ONE counter atomic per block.
// ---------------------------------------------------------------------------
__global__ __launch_bounds__(256) void build_slot2_kernel(
        const float* __restrict__ mask,
        int* __restrict__ slot,
        int* __restrict__ counter) {
    const int tid = threadIdx.x;
    const int gid = blockIdx.x * 256 + tid;     // over NPIX/4 groups
    const float4 m = reinterpret_cast<const float4*>(mask)[gid];
    const int c0 = (m.x != 0.f) + (m.y != 0.f) + (m.z != 0.f) + (m.w != 0.f);

    const int lane = tid & 63;
    const int wv = tid >> 6;
    int pre = c0;
#pragma unroll
    for (int d = 1; d < 64; d <<= 1) {
        int t = __shfl_up(pre, d);
        if (lane >= d) pre += t;
    }

    __shared__ int wsum[4];
    __shared__ int wbase[4];
    __shared__ int blockbase;
    if (lane == 63) wsum[wv] = pre;
    __syncthreads();
    if (tid == 0) {
        int s = 0;
#pragma unroll
        for (int w = 0; w < 4; ++w) { wbase[w] = s; s += wsum[w]; }
        blockbase = atomicAdd(counter, s);
    }
    __syncthreads();

    int s0 = blockbase + wbase[wv] + (pre - c0);
    int4 sv;
    sv.x = (m.x != 0.f) ? s0++ : -1;
    sv.y = (m.y != 0.f) ? s0++ : -1;
    sv.z = (m.z != 0.f) ? s0++ : -1;
    sv.w = (m.w != 0.f) ? s0++ : -1;
    reinterpret_cast<int4*>(slot)[gid] = sv;
}

// ---------------------------------------------------------------------------
// Weight transpose + bf16 convert:  kt[tap][c][i] = bf16(kern[tap][i][c])
// ---------------------------------------------------------------------------
__global__ void convert_kt_kernel(const float* __restrict__ kern,
                                  short* __restrict__ kt) {
    int t = blockIdx.x * 256 + threadIdx.x;
    if (t < 9 * NIN * NOUT) {
        int tap = t >> 12;
        int rem = t & 4095;
        int c = rem >> 6;          // out channel
        int i = rem & 63;          // in channel
        kt[tap * 4096 + c * 64 + i] = f2bf(kern[tap * 4096 + i * 64 + c]);
    }
}

// ---------------------------------------------------------------------------
// Conv via MFMA, v2 (R8 + latency fixes).
// R8 evidence: conv at 93 us with VALU 6.9%/MFMA 3.9%/HBM 12% — latency-
// bound on NINE serialized random slot-gather round trips (one per tap:
// scattered load -> waitcnt -> ballot -> next tap). Fix 1: hoist all 9
// probes before the tap loop — 9 independent loads overlap in ONE vmcnt
// round trip. Fix 2: A-gather via float4 (16 -> 4 load instrs per lane).
// Datapath unchanged (R8-verified, absmax 0.031):
//   A[m=lane&15][k=q*8+j], B[k=q*8+j][n=lane&15], C/D col=lane&15 row=q*4+r.
// ---------------------------------------------------------------------------
__global__ __launch_bounds__(256) void conv_mfma2_kernel(
        const float* __restrict__ values,   // (N_NZ, NIN) fp32
        const short* __restrict__ kt,       // (9, NOUT, NIN) bf16 transposed
        const int* __restrict__ idx,        // (N_NZ, 3) int32
        const int* __restrict__ slot,       // (NPIX,) slot or -1
        float* __restrict__ compact) {      // (MAX_ALIVE, NOUT) zeroed
    const int wid  = threadIdx.x >> 6;      // wave 0..3
    const int lane = threadIdx.x & 63;
    const int q    = lane >> 4;             // quad 0..3
    const int col  = lane & 15;
    const int p0   = blockIdx.x * 64 + wid * 16;   // this wave's 16 points

    // ---- probe coords for this lane's point ----
    const int pme = p0 + col;
    const int b = idx[pme * 3 + 0];
    const int y = idx[pme * 3 + 1];
    const int x = idx[pme * 3 + 2];

    // ---- hoisted: all 9 slot probes issued together (1 round trip) ----
    int sarr[9];
#pragma unroll
    for (int tap = 0; tap < 9; ++tap) {
        const int ky = tap / 3, kx = tap % 3;
        const int sy = min(max(y + ky - 1, 0), HH - 1);
        const int sx = min(max(x + kx - 1, 0), WW - 1);
        sarr[tap] = slot[(b * HH + sy) * WW + sx];
    }

    // ---- A fragments: 16 points x 64 in-ch, float4 loads, fp32 -> bf16 ----
    const float4* v4 = (const float4*)(values + (size_t)(p0 + col) * NIN + q * 8);
    const float4 va0 = v4[0], va1 = v4[1];        // k = q*8 .. q*8+7
    const float4 vb0 = v4[8], vb1 = v4[9];        // k = 32+q*8 ..
    s8v a0, a1;
    a0[0] = f2bf(va0.x); a0[1] = f2bf(va0.y); a0[2] = f2bf(va0.z); a0[3] = f2bf(va0.w);
    a0[4] = f2bf(va1.x); a0[5] = f2bf(va1.y); a0[6] = f2bf(va1.z); a0[7] = f2bf(va1.w);
    a1[0] = f2bf(vb0.x); a1[1] = f2bf(vb0.y); a1[2] = f2bf(vb0.z); a1[3] = f2bf(vb0.w);
    a1[4] = f2bf(vb1.x); a1[5] = f2bf(vb1.y); a1[6] = f2bf(vb1.z); a1[7] = f2bf(vb1.w);

#pragma unroll
    for (int tap = 0; tap < 9; ++tap) {
        const int s = sarr[tap];
        if (__ballot(s >= 0) == 0ULL) continue;   // whole 16-group dead

        const short* kb = kt + tap * 4096 + col * 64 + q * 8;

        f4v c0 = {0.f, 0.f, 0.f, 0.f};
        f4v c1 = {0.f, 0.f, 0.f, 0.f};
        f4v c2 = {0.f, 0.f, 0.f, 0.f};
        f4v c3 = {0.f, 0.f, 0.f, 0.f};

        s8v b0a = *(const s8v*)(kb + 0 * 1024);
        s8v b0b = *(const s8v*)(kb + 0 * 1024 + 32);
        c0 = __builtin_amdgcn_mfma_f32_16x16x32_bf16(a0, b0a, c0, 0, 0, 0);
        c0 = __builtin_amdgcn_mfma_f32_16x16x32_bf16(a1, b0b, c0, 0, 0, 0);
        s8v b1a = *(const s8v*)(kb + 1 * 1024);
        s8v b1b = *(const s8v*)(kb + 1 * 1024 + 32);
        c1 = __builtin_amdgcn_mfma_f32_16x16x32_bf16(a0, b1a, c1, 0, 0, 0);
        c1 = __builtin_amdgcn_mfma_f32_16x16x32_bf16(a1, b1b, c1, 0, 0, 0);
        s8v b2a = *(const s8v*)(kb + 2 * 1024);
        s8v b2b = *(const s8v*)(kb + 2 * 1024 + 32);
        c2 = __builtin_amdgcn_mfma_f32_16x16x32_bf16(a0, b2a, c2, 0, 0, 0);
        c2 = __builtin_amdgcn_mfma_f32_16x16x32_bf16(a1, b2b, c2, 0, 0, 0);
        s8v b3a = *(const s8v*)(kb + 3 * 1024);
        s8v b3b = *(const s8v*)(kb + 3 * 1024 + 32);
        c3 = __builtin_amdgcn_mfma_f32_16x16x32_bf16(a0, b3a, c3, 0, 0, 0);
        c3 = __builtin_amdgcn_mfma_f32_16x16x32_bf16(a1, b3b, c3, 0, 0, 0);

        // ---- scatter alive rows: D row = q*4+r, channel = 16*tile + col ----
#pragma unroll
        for (int r = 0; r < 4; ++r) {
            const int mr = q * 4 + r;           // point row 0..15
            const int sr = __shfl(s, mr);       // its slot
            if (sr >= 0) {
                float* dst = compact + (size_t)sr * NOUT + col;
                atomicAdd(dst + 0,  c0[r]);
                atomicAdd(dst + 16, c1[r]);
                atomicAdd(dst + 32, c2[r]);
                atomicAdd(dst + 48, c3[r]);
            }
        }
    }
}

// ---------------------------------------------------------------------------
// Streaming finalize: writes EVERY output element exactly once.
// ---------------------------------------------------------------------------
__global__ void finalize2_kernel(float* __restrict__ out,
                                 const float* __restrict__ mask,
                                 const int* __restrict__ slot,
                                 const float* __restrict__ compact,
                                 const float* __restrict__ bias) {
    const int t = blockIdx.x * blockDim.x + threadIdx.x;
    const int p = t >> 4;
    const int c4 = (t & 15) * 4;
    if (p >= NPIX) return;
    float4* o = reinterpret_cast<float4*>(out + (size_t)p * NOUT + c4);
    const int s = slot[p];
    if (s < 0) {
        *o = make_float4(0.f, 0.f, 0.f, 0.f);
        return;
    }
    const float m = mask[p];
    const float4 bb = *reinterpret_cast<const float4*>(bias + c4);
    float4 v = *reinterpret_cast<const float4*>(compact + (size_t)s * NOUT + c4);
    v.x = (v.x + m * bb.x) * m;
    v.y = (v.y + m * bb.y) * m;
    v.z = (v.z + m * bb.z) * m;
    v.w = (v.w + m * bb.w) * m;
    *o = v;
}

extern "C" void kernel_launch(void* const* d_in, const int* in_sizes, int n_in,
                              void* d_out, int out_size, void* d_ws, size_t ws_size,
                              hipStream_t stream) {
    const float* values      = (const float*)d_in[0];
    const float* kern        = (const float*)d_in[1];
    const float* bias        = (const float*)d_in[2];
    const float* mask_values = (const float*)d_in[3];
    const int*   indices     = (const int*)d_in[4];
    const int*   mask_idx    = (const int*)d_in[5];
    float* out = (float*)d_out;

    char* ws = (char*)d_ws;
    int*   counter = (int*)ws;
    float* mask    = (float*)(ws + WS_MASK_OFF);
    int*   slot    = (int*)(ws + WS_SLOT_OFF);
    float* compact = (float*)(ws + WS_CMP_OFF);
    short* kt      = (short*)(ws + WS_KT_OFF);

    hipMemsetAsync(ws, 0, WS_NEED, stream);   // counter+mask+slot+compact

    mask_scatter_kernel<<<(N_MASK + 255) / 256, 256, 0, stream>>>(
        mask_values, mask_idx, mask);
    build_slot2_kernel<<<NPIX / 4 / 256, 256, 0, stream>>>(
        mask, slot, counter);
    convert_kt_kernel<<<(9 * NIN * NOUT + 255) / 256, 256, 0, stream>>>(
        kern, kt);

    conv_mfma2_kernel<<<N_NZ / 64, 256, 0, stream>>>(
        values, kt, indices, slot, compact);

    const int total = NPIX * (NOUT / 4);
    finalize2_kernel<<<(total + 255) / 256, 256, 0, stream>>>(
        out, mask, slot, compact, bias);
}